// Round 5
// baseline (2476.448 us; speedup 1.0000x reference)
//
#include <hip/hip_runtime.h>
#include <cstddef>

#define NN 100000
#define NE 1600000
#define D 128
#define D2 256
#define EF 7
#define NL 5
#define BN_EPS 1e-5f

typedef unsigned short ushort_t;
typedef __attribute__((ext_vector_type(8))) short bf16x8;
typedef __attribute__((ext_vector_type(4))) float f32x4;

__device__ __forceinline__ void atomAddF(float* p, float v) { unsafeAtomicAdd(p, v); }

__device__ __forceinline__ unsigned f2bf1(float f) {
    unsigned u = __builtin_bit_cast(unsigned, f);
    return (u + 0x7FFFu + ((u >> 16) & 1u)) >> 16;   // RNE
}
__device__ __forceinline__ float bf2f(unsigned s16) {
    unsigned u = s16 << 16;
    return __builtin_bit_cast(float, u);
}

// ---------------- CSR build ----------------
__global__ __launch_bounds__(256)
void hist_kernel(const int* __restrict__ ei, int* __restrict__ counts)
{
    const int e = blockIdx.x * 256 + threadIdx.x;
    if (e < NE) atomicAdd(&counts[ei[NE + e]], 1);
}

__global__ __launch_bounds__(1024)
void scan_kernel(const int* __restrict__ counts, int* __restrict__ offs)
{
    __shared__ int ssum[1024];
    const int t = threadIdx.x;
    const int per = (NN + 1023) / 1024;
    const int base = t * per;
    int local = 0;
    for (int j = 0; j < per; ++j) {
        const int i = base + j;
        if (i < NN) local += counts[i];
    }
    ssum[t] = local;
    __syncthreads();
    for (int off = 1; off < 1024; off <<= 1) {
        int v = 0;
        if (t >= off) v = ssum[t - off];
        __syncthreads();
        ssum[t] += v;
        __syncthreads();
    }
    int run = ssum[t] - local;
    for (int j = 0; j < per; ++j) {
        const int i = base + j;
        if (i < NN) { offs[i] = run; run += counts[i]; }
    }
    if (t == 1023) offs[NN] = NE;
}

// scatter edges into dst-sorted order; edge features fp32 [8] (7 used)
__global__ __launch_bounds__(256)
void scatter_kernel(const int* __restrict__ ei, const float* __restrict__ ea,
                    int* __restrict__ offmut, int* __restrict__ sSrc,
                    float* __restrict__ sEaF)
{
    const int e = blockIdx.x * 256 + threadIdx.x;
    if (e < NE) {
        const int dst = ei[NE + e];
        const int pos = atomicAdd(&offmut[dst], 1);
        sSrc[pos] = ei[e];
        const float* eap = &ea[(size_t)e * EF];
        const float4 a = {eap[0], eap[1], eap[2], eap[3]};
        const float4 b = {eap[4], eap[5], eap[6], 0.f};
        *(float4*)&sEaF[(size_t)pos * 8] = a;
        *(float4*)&sEaF[(size_t)pos * 8 + 4] = b;
    }
}

// ---------------- weight convert: W1[l][k][n]->W1t[l][n][k] bf16, W2 same ----------------
__global__ __launch_bounds__(256)
void wconv_kernel(const float* __restrict__ W1, const float* __restrict__ W2,
                  ushort_t* __restrict__ W1t, ushort_t* __restrict__ W2t)
{
    const int idx = blockIdx.x * 256 + threadIdx.x;
    const int per = D * D2;
    if (idx < NL * per) {
        const int l = idx / per, r = idx % per;
        const int k1 = r / D2, n1 = r % D2;            // W1: [128][256]
        W1t[(size_t)l * per + n1 * D + k1] = (ushort_t)f2bf1(W1[idx]);
        const int k2 = r / D, n2 = r % D;              // W2: [256][128]
        W2t[(size_t)l * per + n2 * D2 + k2] = (ushort_t)f2bf1(W2[idx]);
    }
}

// ---------------- gather: xin[n] = (1+eps)*h(n) + sum_e relu(h(src)+ee) ----------------
// h = hAct (fp32, post-BN+relu). Software-pipelined: src 2 ahead, h/ea 1 ahead.
#define GWAVES 25000
template<int L0>
__global__ __launch_bounds__(256)
void gather_kernel(const int* __restrict__ offs, const int* __restrict__ sSrc,
                   const float* __restrict__ sEaF,
                   const float* __restrict__ We, const float* __restrict__ be,
                   const float* __restrict__ hAct, const float* __restrict__ h0,
                   const float* __restrict__ epsp,
                   float* __restrict__ xinF, float* __restrict__ xsum)
{
    __shared__ __align__(16) float sCS[4][D];
    const int lane = threadIdx.x & 63;
    const int w = threadIdx.x >> 6;
    const int wid = blockIdx.x * 4 + w;
    const float2* We2 = (const float2*)We;
    const float2* hA2 = (const float2*)hAct;
    float2 wv[EF];
    #pragma unroll
    for (int k = 0; k < EF; ++k) wv[k] = We2[k * 64 + lane];
    const float2 bev = ((const float2*)be)[lane];
    float2 h0v = {0.f, 0.f};
    if (L0) h0v = ((const float2*)h0)[lane];
    const float epsv = 1.0f + *epsp;

    float2 cs = {0.f, 0.f};
    #pragma unroll 1
    for (int it = 0; it < 4; ++it) {
        const int n = wid + it * GWAVES;
        if (n >= NN) break;
        const int s = offs[n], en = offs[n + 1];
        float2 acc = {0.f, 0.f};
        if (s < en) {
            int srcN = sSrc[s];                                  // src for p
            float2 hc;
            if (L0) hc = h0v; else hc = hA2[(srcN << 6) + lane];
            srcN = sSrc[min(s + 1, en - 1)];                     // src for p+1
            float4 ea0 = *(const float4*)&sEaF[(size_t)s * 8];
            float4 ea1 = *(const float4*)&sEaF[(size_t)s * 8 + 4];
            for (int p = s; p < en; ++p) {
                const int pn = min(p + 1, en - 1);
                const int srcNN = sSrc[min(p + 2, en - 1)];
                float2 hn;
                if (L0) hn = h0v; else hn = hA2[(srcN << 6) + lane];
                const float4 ea0n = *(const float4*)&sEaF[(size_t)pn * 8];
                const float4 ea1n = *(const float4*)&sEaF[(size_t)pn * 8 + 4];
                float2 m = bev;
                m.x = fmaf(ea0.x, wv[0].x, m.x); m.y = fmaf(ea0.x, wv[0].y, m.y);
                m.x = fmaf(ea0.y, wv[1].x, m.x); m.y = fmaf(ea0.y, wv[1].y, m.y);
                m.x = fmaf(ea0.z, wv[2].x, m.x); m.y = fmaf(ea0.z, wv[2].y, m.y);
                m.x = fmaf(ea0.w, wv[3].x, m.x); m.y = fmaf(ea0.w, wv[3].y, m.y);
                m.x = fmaf(ea1.x, wv[4].x, m.x); m.y = fmaf(ea1.x, wv[4].y, m.y);
                m.x = fmaf(ea1.y, wv[5].x, m.x); m.y = fmaf(ea1.y, wv[5].y, m.y);
                m.x = fmaf(ea1.z, wv[6].x, m.x); m.y = fmaf(ea1.z, wv[6].y, m.y);
                acc.x += fmaxf(hc.x + m.x, 0.f);
                acc.y += fmaxf(hc.y + m.y, 0.f);
                hc = hn; ea0 = ea0n; ea1 = ea1n; srcN = srcNN;
            }
        }
        float2 hs;
        if (L0) hs = h0v; else hs = hA2[(n << 6) + lane];
        acc.x = fmaf(epsv, hs.x, acc.x);
        acc.y = fmaf(epsv, hs.y, acc.y);
        cs.x += acc.x; cs.y += acc.y;
        *(float2*)&xinF[((size_t)n << 7) + 2 * lane] = acc;
    }
    sCS[w][2 * lane] = cs.x;
    sCS[w][2 * lane + 1] = cs.y;
    __syncthreads();
    if (threadIdx.x < D) {
        atomAddF(&xsum[threadIdx.x],
                 sCS[0][threadIdx.x] + sCS[1][threadIdx.x] +
                 sCS[2][threadIdx.x] + sCS[3][threadIdx.x]);
    }
}

// ---------------- mm1: z1c = (xin - colmean) @ W1 (bf16 MFMA), fused stats ----------------
__global__ __launch_bounds__(256, 2)
void mm1_kernel(const float* __restrict__ xinF, const float* __restrict__ xsum,
                const ushort_t* __restrict__ W1t,
                ushort_t* __restrict__ z1B, float* __restrict__ stats)
{
    __shared__ __align__(16) ushort_t sA[64 * 128];
    __shared__ __align__(16) float sM[D];
    const int t = threadIdx.x;
    if (t < D) sM[t] = xsum[t] * (1.0f / (float)NN);
    const int i0 = blockIdx.x * 64;
    const int lane = t & 63, w = t >> 6;
    const int nb = w * 64;

    bf16x8 bfr[4][4];
    #pragma unroll
    for (int nt = 0; nt < 4; ++nt)
        #pragma unroll
        for (int ks = 0; ks < 4; ++ks) {
            const int n = nb + nt * 16 + (lane & 15);
            const int k = ks * 32 + (lane >> 4) * 8;
            bfr[nt][ks] = *(const bf16x8*)&W1t[n * D + k];
        }
    __syncthreads();   // sM visible

    #pragma unroll
    for (int p = 0; p < 4; ++p) {
        const int linear = p * 256 + t;
        const int row = linear >> 4, ch = linear & 15;
        const int gi = i0 + row;
        unsigned oo[4] = {0, 0, 0, 0};
        if (gi < NN) {
            const float4 a = *(const float4*)&xinF[(size_t)gi * D + ch * 8];
            const float4 b = *(const float4*)&xinF[(size_t)gi * D + ch * 8 + 4];
            const float vv[8] = {a.x, a.y, a.z, a.w, b.x, b.y, b.z, b.w};
            #pragma unroll
            for (int j2 = 0; j2 < 4; ++j2) {
                const int c0 = ch * 8 + j2 * 2;
                const float lo = vv[2 * j2]     - sM[c0];
                const float hi = vv[2 * j2 + 1] - sM[c0 + 1];
                oo[j2] = f2bf1(lo) | (f2bf1(hi) << 16);
            }
        }
        unsigned boff = (unsigned)(row * 256 + ch * 16);
        boff ^= (unsigned)((row & 7) << 4);
        *(uint4*)((char*)sA + boff) = make_uint4(oo[0], oo[1], oo[2], oo[3]);
    }
    __syncthreads();

    f32x4 acc[4][4];
    #pragma unroll
    for (int a = 0; a < 4; ++a)
        #pragma unroll
        for (int b = 0; b < 4; ++b) acc[a][b] = (f32x4){0.f, 0.f, 0.f, 0.f};

    #pragma unroll
    for (int mt = 0; mt < 4; ++mt) {
        bf16x8 af[4];
        #pragma unroll
        for (int ks = 0; ks < 4; ++ks) {
            const int row = mt * 16 + (lane & 15);
            unsigned boff = (unsigned)(row * 256 + ks * 64 + (lane >> 4) * 16);
            boff ^= (unsigned)((row & 7) << 4);
            af[ks] = *(const bf16x8*)((const char*)sA + boff);
        }
        #pragma unroll
        for (int nt = 0; nt < 4; ++nt)
            #pragma unroll
            for (int ks = 0; ks < 4; ++ks)
                acc[mt][nt] = __builtin_amdgcn_mfma_f32_16x16x32_bf16(af[ks], bfr[nt][ks], acc[mt][nt], 0, 0, 0);
    }

    float s[4], q[4];
    #pragma unroll
    for (int nt = 0; nt < 4; ++nt) { s[nt] = 0.f; q[nt] = 0.f; }
    #pragma unroll
    for (int nt = 0; nt < 4; ++nt) {
        const int n = nb + nt * 16 + (lane & 15);
        #pragma unroll
        for (int mt = 0; mt < 4; ++mt)
            #pragma unroll
            for (int r = 0; r < 4; ++r) {
                const int i = i0 + mt * 16 + (lane >> 4) * 4 + r;
                if (i < NN) {
                    const float v = acc[mt][nt][r];
                    s[nt] += v; q[nt] = fmaf(v, v, q[nt]);
                    z1B[(size_t)i * D2 + n] = (ushort_t)f2bf1(v);
                }
            }
    }
    #pragma unroll
    for (int nt = 0; nt < 4; ++nt) {
        s[nt] += __shfl_xor(s[nt], 16, 64); s[nt] += __shfl_xor(s[nt], 32, 64);
        q[nt] += __shfl_xor(q[nt], 16, 64); q[nt] += __shfl_xor(q[nt], 32, 64);
    }
    if (lane < 16) {
        #pragma unroll
        for (int nt = 0; nt < 4; ++nt) {
            const int n = nb + nt * 16 + lane;
            atomAddF(&stats[n], s[nt]);
            atomAddF(&stats[D2 + n], q[nt]);
        }
    }
}

// ---------------- ymean: ysum[c] = sum_rows relu(a*z1c+cc); aff computed inline ----------------
#define YROWS 391
__global__ __launch_bounds__(256)
void ymean_kernel(const ushort_t* __restrict__ z1B, const float* __restrict__ stats1,
                  const float* __restrict__ g1, const float* __restrict__ bt1,
                  float* __restrict__ ysum)
{
    __shared__ float sAf[2 * D2];
    __shared__ float sR[4][D2];
    const int t = threadIdx.x;
    {
        const float inv = 1.0f / (float)NN;
        const float mu = stats1[t] * inv;
        const float var = fmaf(-mu, mu, stats1[D2 + t] * inv);
        const float a = g1[t] * rsqrtf(var + BN_EPS);
        sAf[t] = a;
        sAf[D2 + t] = fmaf(-a, mu, bt1[t]);
    }
    __syncthreads();
    const int c0 = (t & 63) * 4;
    const int rg = t >> 6;
    const float a0 = sAf[c0], a1 = sAf[c0 + 1], a2 = sAf[c0 + 2], a3 = sAf[c0 + 3];
    const float b0 = sAf[D2 + c0], b1 = sAf[D2 + c0 + 1], b2 = sAf[D2 + c0 + 2], b3 = sAf[D2 + c0 + 3];
    float s0 = 0.f, s1 = 0.f, s2 = 0.f, s3 = 0.f;
    const int rend = min(NN, (blockIdx.x + 1) * YROWS);
    for (int r = blockIdx.x * YROWS + rg; r < rend; r += 4) {
        const uint2 v = *(const uint2*)&z1B[(size_t)r * D2 + c0];
        s0 += fmaxf(fmaf(a0, bf2f(v.x & 0xFFFFu), b0), 0.f);
        s1 += fmaxf(fmaf(a1, bf2f(v.x >> 16),     b1), 0.f);
        s2 += fmaxf(fmaf(a2, bf2f(v.y & 0xFFFFu), b2), 0.f);
        s3 += fmaxf(fmaf(a3, bf2f(v.y >> 16),     b3), 0.f);
    }
    sR[rg][c0] = s0; sR[rg][c0 + 1] = s1; sR[rg][c0 + 2] = s2; sR[rg][c0 + 3] = s3;
    __syncthreads();
    if (t < D2) atomAddF(&ysum[t], sR[0][t] + sR[1][t] + sR[2][t] + sR[3][t]);
}

// ---------------- mm2: z2c = (relu(aff1(z1c)) - ymean) @ W2 (bf16 MFMA), fp32 out ----------------
__global__ __launch_bounds__(256, 2)
void mm2_kernel(const ushort_t* __restrict__ z1B, const float* __restrict__ stats1,
                const float* __restrict__ g1, const float* __restrict__ bt1,
                const float* __restrict__ ysum, const ushort_t* __restrict__ W2t,
                float* __restrict__ z2F, float* __restrict__ stats2)
{
    __shared__ __align__(16) ushort_t sA[64 * 256];
    __shared__ __align__(16) float sAff[2 * D2];
    __shared__ __align__(16) float sYm[D2];
    const int t = threadIdx.x;
    {
        const float inv = 1.0f / (float)NN;
        const float mu = stats1[t] * inv;
        const float var = fmaf(-mu, mu, stats1[D2 + t] * inv);
        const float a = g1[t] * rsqrtf(var + BN_EPS);
        sAff[t] = a;
        sAff[D2 + t] = fmaf(-a, mu, bt1[t]);
        sYm[t] = ysum[t] * inv;
    }
    const int i0 = blockIdx.x * 64;
    const int lane = t & 63, w = t >> 6;
    const int nb = w * 32;

    bf16x8 bfr[2][8];
    #pragma unroll
    for (int nt = 0; nt < 2; ++nt)
        #pragma unroll
        for (int ks = 0; ks < 8; ++ks) {
            const int n = nb + nt * 16 + (lane & 15);
            const int k = ks * 32 + (lane >> 4) * 8;
            bfr[nt][ks] = *(const bf16x8*)&W2t[n * D2 + k];
        }
    __syncthreads();   // sAff/sYm visible

    #pragma unroll
    for (int p = 0; p < 8; ++p) {
        const int linear = p * 256 + t;
        const int row = linear >> 5, ch = linear & 31;
        const int gi = i0 + row;
        uint4 v = make_uint4(0, 0, 0, 0);
        if (gi < NN) v = *(const uint4*)&z1B[(size_t)gi * D2 + ch * 8];
        unsigned uu[4] = {v.x, v.y, v.z, v.w};
        unsigned oo[4] = {0, 0, 0, 0};
        if (gi < NN) {
            #pragma unroll
            for (int j2 = 0; j2 < 4; ++j2) {
                const int c0 = ch * 8 + j2 * 2;
                float lo = bf2f(uu[j2] & 0xFFFFu);
                float hi = bf2f(uu[j2] >> 16);
                lo = fmaxf(fmaf(sAff[c0], lo, sAff[D2 + c0]), 0.f) - sYm[c0];
                hi = fmaxf(fmaf(sAff[c0 + 1], hi, sAff[D2 + c0 + 1]), 0.f) - sYm[c0 + 1];
                oo[j2] = f2bf1(lo) | (f2bf1(hi) << 16);
            }
        }
        unsigned boff = (unsigned)(row * 512 + ch * 16);
        boff ^= (unsigned)((row & 7) << 4);
        *(uint4*)((char*)sA + boff) = make_uint4(oo[0], oo[1], oo[2], oo[3]);
    }
    __syncthreads();

    f32x4 acc[4][2];
    #pragma unroll
    for (int a = 0; a < 4; ++a)
        #pragma unroll
        for (int b = 0; b < 2; ++b) acc[a][b] = (f32x4){0.f, 0.f, 0.f, 0.f};

    #pragma unroll
    for (int mt = 0; mt < 4; ++mt) {
        bf16x8 af[8];
        #pragma unroll
        for (int ks = 0; ks < 8; ++ks) {
            const int row = mt * 16 + (lane & 15);
            unsigned boff = (unsigned)(row * 512 + ks * 64 + (lane >> 4) * 16);
            boff ^= (unsigned)((row & 7) << 4);
            af[ks] = *(const bf16x8*)((const char*)sA + boff);
        }
        #pragma unroll
        for (int nt = 0; nt < 2; ++nt)
            #pragma unroll
            for (int ks = 0; ks < 8; ++ks)
                acc[mt][nt] = __builtin_amdgcn_mfma_f32_16x16x32_bf16(af[ks], bfr[nt][ks], acc[mt][nt], 0, 0, 0);
    }

    float s[2], q[2];
    #pragma unroll
    for (int nt = 0; nt < 2; ++nt) { s[nt] = 0.f; q[nt] = 0.f; }
    #pragma unroll
    for (int nt = 0; nt < 2; ++nt) {
        const int n = nb + nt * 16 + (lane & 15);
        #pragma unroll
        for (int mt = 0; mt < 4; ++mt)
            #pragma unroll
            for (int r = 0; r < 4; ++r) {
                const int i = i0 + mt * 16 + (lane >> 4) * 4 + r;
                if (i < NN) {
                    const float v = acc[mt][nt][r];
                    s[nt] += v; q[nt] = fmaf(v, v, q[nt]);
                    z2F[(size_t)i * D + n] = v;
                }
            }
    }
    #pragma unroll
    for (int nt = 0; nt < 2; ++nt) {
        s[nt] += __shfl_xor(s[nt], 16, 64); s[nt] += __shfl_xor(s[nt], 32, 64);
        q[nt] += __shfl_xor(q[nt], 16, 64); q[nt] += __shfl_xor(q[nt], 32, 64);
    }
    if (lane < 16) {
        #pragma unroll
        for (int nt = 0; nt < 2; ++nt) {
            const int n = nb + nt * 16 + lane;
            atomAddF(&stats2[n], s[nt]);
            atomAddF(&stats2[D + n], q[nt]);
        }
    }
}

// ---------------- act: dst = [relu](aff2(z2)); aff computed inline from stats2 ----------------
template<int RELU>
__global__ __launch_bounds__(256)
void act_kernel(const float* __restrict__ z2F, const float* __restrict__ stats2,
                const float* __restrict__ g, const float* __restrict__ bt,
                float* __restrict__ dst)
{
    __shared__ float sA[D], sC[D];
    const int t = threadIdx.x;
    if (t < D) {
        const float inv = 1.0f / (float)NN;
        const float mu = stats2[t] * inv;
        const float var = fmaf(-mu, mu, stats2[D + t] * inv);
        const float a = g[t] * rsqrtf(var + BN_EPS);
        sA[t] = a;
        sC[t] = fmaf(-a, mu, bt[t]);
    }
    __syncthreads();
    const int idx = blockIdx.x * 256 + t;  // float4 index
    if (idx < NN * D / 4) {
        const int d0 = (idx * 4) & (D - 1);
        const float4 v = *(const float4*)&z2F[(size_t)idx * 4];
        float4 o;
        o.x = fmaf(sA[d0 + 0], v.x, sC[d0 + 0]);
        o.y = fmaf(sA[d0 + 1], v.y, sC[d0 + 1]);
        o.z = fmaf(sA[d0 + 2], v.z, sC[d0 + 2]);
        o.w = fmaf(sA[d0 + 3], v.w, sC[d0 + 3]);
        if (RELU) {
            o.x = fmaxf(o.x, 0.f); o.y = fmaxf(o.y, 0.f);
            o.z = fmaxf(o.z, 0.f); o.w = fmaxf(o.w, 0.f);
        }
        *(float4*)&dst[(size_t)idx * 4] = o;
    }
}

extern "C" void kernel_launch(void* const* d_in, const int* in_sizes, int n_in,
                              void* d_out, int out_size, void* d_ws, size_t ws_size,
                              hipStream_t stream)
{
    (void)in_sizes; (void)n_in; (void)out_size; (void)ws_size;
    const int*   ei       = (const int*)d_in[1];
    const float* ea       = (const float*)d_in[2];
    const float* node_emb = (const float*)d_in[3];
    const float* We       = (const float*)d_in[4];
    const float* be       = (const float*)d_in[5];
    const float* eps      = (const float*)d_in[6];
    const float* W1       = (const float*)d_in[7];
    const float* g1       = (const float*)d_in[9];
    const float* bt1      = (const float*)d_in[10];
    const float* W2       = (const float*)d_in[11];
    const float* gbn      = (const float*)d_in[13];
    const float* bbn      = (const float*)d_in[14];
    float* out = (float*)d_out;

    char* base = (char*)d_ws;
    size_t off = 0;
    auto alloc = [&](size_t bytes) -> void* {
        void* p = base + off;
        off = (off + bytes + 255) & ~(size_t)255;
        return p;
    };
    float*    tmpF   = (float*)alloc((size_t)NN * D * 4);      // xin (gather->mm1), z2 (mm2->act)
    ushort_t* z1B    = (ushort_t*)alloc((size_t)NN * D2 * 2);
    float*    hAct   = (float*)alloc((size_t)NN * D * 4);
    ushort_t* W1t    = (ushort_t*)alloc((size_t)NL * D * D2 * 2);
    ushort_t* W2t    = (ushort_t*)alloc((size_t)NL * D * D2 * 2);
    float*    red    = (float*)alloc(1152 * sizeof(float));
    float*    stats1 = red;            // 512
    float*    stats2 = red + 512;      // 256
    float*    xsum   = red + 768;      // 128
    float*    ysum   = red + 896;      // 256
    int*      counts = (int*)alloc((NN + 1) * sizeof(int));
    int*      offs   = (int*)alloc((NN + 1) * sizeof(int));
    int*      offmut = (int*)alloc(NN * sizeof(int));
    int*      sSrc   = (int*)alloc((size_t)NE * sizeof(int));
    float*    sEaF   = (float*)alloc((size_t)NE * 8 * sizeof(float));

    // ---- CSR build + weight conversion ----
    hipMemsetAsync(counts, 0, (NN + 1) * sizeof(int), stream);
    hist_kernel<<<(NE + 255) / 256, 256, 0, stream>>>(ei, counts);
    scan_kernel<<<1, 1024, 0, stream>>>(counts, offs);
    hipMemcpyAsync(offmut, offs, NN * sizeof(int), hipMemcpyDeviceToDevice, stream);
    scatter_kernel<<<(NE + 255) / 256, 256, 0, stream>>>(ei, ea, offmut, sSrc, sEaF);
    wconv_kernel<<<(NL * D * D2 + 255) / 256, 256, 0, stream>>>(W1, W2, W1t, W2t);

    for (int l = 0; l < NL; ++l) {
        hipMemsetAsync(red, 0, 1152 * sizeof(float), stream);
        if (l == 0) {
            gather_kernel<1><<<6250, 256, 0, stream>>>(offs, sSrc, sEaF,
                                                       We + l * EF * D, be + l * D,
                                                       hAct, node_emb, eps + l, tmpF, xsum);
        } else {
            gather_kernel<0><<<6250, 256, 0, stream>>>(offs, sSrc, sEaF,
                                                       We + l * EF * D, be + l * D,
                                                       hAct, node_emb, eps + l, tmpF, xsum);
        }
        mm1_kernel<<<(NN + 63) / 64, 256, 0, stream>>>(tmpF, xsum, W1t + (size_t)l * D * D2,
                                                       z1B, stats1);
        ymean_kernel<<<256, 256, 0, stream>>>(z1B, stats1, g1 + l * D2, bt1 + l * D2, ysum);
        mm2_kernel<<<(NN + 63) / 64, 256, 0, stream>>>(z1B, stats1, g1 + l * D2, bt1 + l * D2,
                                                       ysum, W2t + (size_t)l * D * D2,
                                                       tmpF, stats2);
        if (l < NL - 1) {
            act_kernel<1><<<(NN * D / 4 + 255) / 256, 256, 0, stream>>>(
                tmpF, stats2, gbn + l * D, bbn + l * D, hAct);
        } else {
            act_kernel<0><<<(NN * D / 4 + 255) / 256, 256, 0, stream>>>(
                tmpF, stats2, gbn + l * D, bbn + l * D, out);
        }
    }
}

// Round 6
// 2109.075 us; speedup vs baseline: 1.1742x; 1.1742x over previous
//
#include <hip/hip_runtime.h>
#include <cstddef>

#define NN 100000
#define NE 1600000
#define D 128
#define D2 256
#define EF 7
#define NL 5
#define BN_EPS 1e-5f

typedef unsigned short ushort_t;
typedef __attribute__((ext_vector_type(8))) _Float16 f16x8;
typedef __attribute__((ext_vector_type(4))) float f32x4;

__device__ __forceinline__ void atomAddF(float* p, float v) { unsafeAtomicAdd(p, v); }

__device__ __forceinline__ ushort_t f2h(float f) {
    return __builtin_bit_cast(ushort_t, (_Float16)f);
}
__device__ __forceinline__ unsigned pk2h(float lo, float hi) {
    return (unsigned)f2h(lo) | ((unsigned)f2h(hi) << 16);
}
__device__ __forceinline__ float h2f(unsigned u16) {
    return (float)__builtin_bit_cast(_Float16, (ushort_t)(u16 & 0xFFFFu));
}

// ---------------- CSR build ----------------
__global__ __launch_bounds__(256)
void hist_kernel(const int* __restrict__ ei, int* __restrict__ counts)
{
    const int e = blockIdx.x * 256 + threadIdx.x;
    if (e < NE) atomicAdd(&counts[ei[NE + e]], 1);
}

__global__ __launch_bounds__(1024)
void scan_kernel(const int* __restrict__ counts, int* __restrict__ offs)
{
    __shared__ int ssum[1024];
    const int t = threadIdx.x;
    const int per = (NN + 1023) / 1024;
    const int base = t * per;
    int local = 0;
    for (int j = 0; j < per; ++j) {
        const int i = base + j;
        if (i < NN) local += counts[i];
    }
    ssum[t] = local;
    __syncthreads();
    for (int off = 1; off < 1024; off <<= 1) {
        int v = 0;
        if (t >= off) v = ssum[t - off];
        __syncthreads();
        ssum[t] += v;
        __syncthreads();
    }
    int run = ssum[t] - local;
    for (int j = 0; j < per; ++j) {
        const int i = base + j;
        if (i < NN) { offs[i] = run; run += counts[i]; }
    }
    if (t == 1023) offs[NN] = NE;
}

// scatter edges into dst-sorted order; pack edge features fp16 [8] (7 used)
__global__ __launch_bounds__(256)
void scatter_kernel(const int* __restrict__ ei, const float* __restrict__ ea,
                    int* __restrict__ offmut, int* __restrict__ sSrc,
                    ushort_t* __restrict__ eaH)
{
    const int e = blockIdx.x * 256 + threadIdx.x;
    if (e < NE) {
        const int dst = ei[NE + e];
        const int pos = atomicAdd(&offmut[dst], 1);
        sSrc[pos] = ei[e];
        const float* eap = &ea[(size_t)e * EF];
        const unsigned o0 = pk2h(eap[0], eap[1]);
        const unsigned o1 = pk2h(eap[2], eap[3]);
        const unsigned o2 = pk2h(eap[4], eap[5]);
        const unsigned o3 = pk2h(eap[6], 0.f);
        *(uint4*)&eaH[(size_t)pos * 8] = make_uint4(o0, o1, o2, o3);
    }
}

// ---------------- weight convert: W1[l][k][n]->W1t[l][n][k] fp16, W2 same ----------------
__global__ __launch_bounds__(256)
void wconv_kernel(const float* __restrict__ W1, const float* __restrict__ W2,
                  ushort_t* __restrict__ W1t, ushort_t* __restrict__ W2t)
{
    const int idx = blockIdx.x * 256 + threadIdx.x;
    const int per = D * D2;
    if (idx < NL * per) {
        const int l = idx / per, r = idx % per;
        const int k1 = r / D2, n1 = r % D2;            // W1: [128][256]
        W1t[(size_t)l * per + n1 * D + k1] = f2h(W1[idx]);
        const int k2 = r / D, n2 = r % D;              // W2: [256][128]
        W2t[(size_t)l * per + n2 * D2 + k2] = f2h(W2[idx]);
    }
}

// ---------------- gather: xin[n] = (1+eps)*h(n) + sum_e relu(h(src)+ee) ----------------
// h = hAct (fp16, post-BN+relu). 4 nodes per wave iterated CONCURRENTLY (4-deep load MLP).
#define GWAVES 25000
template<int L0>
__global__ __launch_bounds__(256)
void gather_kernel(const int* __restrict__ offs, const int* __restrict__ sSrc,
                   const ushort_t* __restrict__ eaH,
                   const float* __restrict__ We, const float* __restrict__ be,
                   const ushort_t* __restrict__ hAct, const float* __restrict__ h0,
                   const float* __restrict__ epsp,
                   float* __restrict__ xinF, float* __restrict__ xsum)
{
    __shared__ __align__(16) float sCS[4][D];
    const int lane = threadIdx.x & 63;
    const int w = threadIdx.x >> 6;
    const int wid = blockIdx.x * 4 + w;
    const float2* We2 = (const float2*)We;
    const unsigned* hU = (const unsigned*)hAct;   // 64 words per row
    float2 wv[EF];
    #pragma unroll
    for (int k = 0; k < EF; ++k) wv[k] = We2[k * 64 + lane];
    const float2 bev = ((const float2*)be)[lane];
    float2 h0v = {0.f, 0.f};
    if (L0) h0v = ((const float2*)h0)[lane];
    const float epsv = 1.0f + *epsp;

    int s4[4], e4[4], p4[4];
    #pragma unroll
    for (int i = 0; i < 4; ++i) {
        const int n = wid + i * GWAVES;               // always < NN (exact division)
        s4[i] = __builtin_amdgcn_readfirstlane(offs[n]);
        e4[i] = __builtin_amdgcn_readfirstlane(offs[n + 1]);
        p4[i] = s4[i];
    }
    const int mx = max(max(e4[0] - s4[0], e4[1] - s4[1]),
                       max(e4[2] - s4[2], e4[3] - s4[3]));

    float2 acc[4];
    #pragma unroll
    for (int i = 0; i < 4; ++i) acc[i] = (float2){0.f, 0.f};

    for (int j = 0; j < mx; ++j) {
        unsigned hw[4];
        uint4 ev[4];
        #pragma unroll
        for (int i = 0; i < 4; ++i) {
            if (p4[i] < e4[i]) {
                const int src = sSrc[p4[i]];
                if (!L0) hw[i] = hU[(src << 6) + lane];
                ev[i] = *(const uint4*)&eaH[(size_t)p4[i] * 8];
            }
        }
        #pragma unroll
        for (int i = 0; i < 4; ++i) {
            if (p4[i] < e4[i]) {
                float2 m = bev;
                {
                    const float e0 = h2f(ev[i].x), e1 = h2f(ev[i].x >> 16);
                    const float e2 = h2f(ev[i].y), e3 = h2f(ev[i].y >> 16);
                    const float e4v = h2f(ev[i].z), e5 = h2f(ev[i].z >> 16);
                    const float e6 = h2f(ev[i].w);
                    m.x = fmaf(e0, wv[0].x, m.x); m.y = fmaf(e0, wv[0].y, m.y);
                    m.x = fmaf(e1, wv[1].x, m.x); m.y = fmaf(e1, wv[1].y, m.y);
                    m.x = fmaf(e2, wv[2].x, m.x); m.y = fmaf(e2, wv[2].y, m.y);
                    m.x = fmaf(e3, wv[3].x, m.x); m.y = fmaf(e3, wv[3].y, m.y);
                    m.x = fmaf(e4v, wv[4].x, m.x); m.y = fmaf(e4v, wv[4].y, m.y);
                    m.x = fmaf(e5, wv[5].x, m.x); m.y = fmaf(e5, wv[5].y, m.y);
                    m.x = fmaf(e6, wv[6].x, m.x); m.y = fmaf(e6, wv[6].y, m.y);
                }
                float2 h;
                if (L0) h = h0v;
                else { h.x = h2f(hw[i]); h.y = h2f(hw[i] >> 16); }
                acc[i].x += fmaxf(h.x + m.x, 0.f);
                acc[i].y += fmaxf(h.y + m.y, 0.f);
                ++p4[i];
            }
        }
    }

    float2 cs = {0.f, 0.f};
    #pragma unroll
    for (int i = 0; i < 4; ++i) {
        const int n = wid + i * GWAVES;
        float2 hs;
        if (L0) hs = h0v;
        else {
            const unsigned hv = hU[(n << 6) + lane];
            hs.x = h2f(hv); hs.y = h2f(hv >> 16);
        }
        float2 a = acc[i];
        a.x = fmaf(epsv, hs.x, a.x);
        a.y = fmaf(epsv, hs.y, a.y);
        cs.x += a.x; cs.y += a.y;
        *(float2*)&xinF[((size_t)n << 7) + 2 * lane] = a;
    }
    sCS[w][2 * lane] = cs.x;
    sCS[w][2 * lane + 1] = cs.y;
    __syncthreads();
    if (threadIdx.x < D) {
        atomAddF(&xsum[threadIdx.x],
                 sCS[0][threadIdx.x] + sCS[1][threadIdx.x] +
                 sCS[2][threadIdx.x] + sCS[3][threadIdx.x]);
    }
}

// ---------------- mm1: z1c = (xin - colmean) @ W1 (fp16 MFMA), fused stats ----------------
__global__ __launch_bounds__(256, 2)
void mm1_kernel(const float* __restrict__ xinF, const float* __restrict__ xsum,
                const ushort_t* __restrict__ W1t,
                ushort_t* __restrict__ z1H, float* __restrict__ stats)
{
    __shared__ __align__(16) ushort_t sA[64 * 128];
    __shared__ __align__(16) float sM[D];
    const int t = threadIdx.x;
    if (t < D) sM[t] = xsum[t] * (1.0f / (float)NN);
    const int i0 = blockIdx.x * 64;
    const int lane = t & 63, w = t >> 6;
    const int nb = w * 64;

    f16x8 bfr[4][4];
    #pragma unroll
    for (int nt = 0; nt < 4; ++nt)
        #pragma unroll
        for (int ks = 0; ks < 4; ++ks) {
            const int n = nb + nt * 16 + (lane & 15);
            const int k = ks * 32 + (lane >> 4) * 8;
            bfr[nt][ks] = *(const f16x8*)&W1t[n * D + k];
        }
    __syncthreads();   // sM visible

    #pragma unroll
    for (int p = 0; p < 4; ++p) {
        const int linear = p * 256 + t;
        const int row = linear >> 4, ch = linear & 15;
        const int gi = i0 + row;
        unsigned oo[4] = {0, 0, 0, 0};
        if (gi < NN) {
            const float4 a = *(const float4*)&xinF[(size_t)gi * D + ch * 8];
            const float4 b = *(const float4*)&xinF[(size_t)gi * D + ch * 8 + 4];
            const float vv[8] = {a.x, a.y, a.z, a.w, b.x, b.y, b.z, b.w};
            #pragma unroll
            for (int j2 = 0; j2 < 4; ++j2) {
                const int c0 = ch * 8 + j2 * 2;
                oo[j2] = pk2h(vv[2 * j2] - sM[c0], vv[2 * j2 + 1] - sM[c0 + 1]);
            }
        }
        unsigned boff = (unsigned)(row * 256 + ch * 16);
        boff ^= (unsigned)((row & 7) << 4);
        *(uint4*)((char*)sA + boff) = make_uint4(oo[0], oo[1], oo[2], oo[3]);
    }
    __syncthreads();

    f32x4 acc[4][4];
    #pragma unroll
    for (int a = 0; a < 4; ++a)
        #pragma unroll
        for (int b = 0; b < 4; ++b) acc[a][b] = (f32x4){0.f, 0.f, 0.f, 0.f};

    #pragma unroll
    for (int mt = 0; mt < 4; ++mt) {
        f16x8 af[4];
        #pragma unroll
        for (int ks = 0; ks < 4; ++ks) {
            const int row = mt * 16 + (lane & 15);
            unsigned boff = (unsigned)(row * 256 + ks * 64 + (lane >> 4) * 16);
            boff ^= (unsigned)((row & 7) << 4);
            af[ks] = *(const f16x8*)((const char*)sA + boff);
        }
        #pragma unroll
        for (int nt = 0; nt < 4; ++nt)
            #pragma unroll
            for (int ks = 0; ks < 4; ++ks)
                acc[mt][nt] = __builtin_amdgcn_mfma_f32_16x16x32_f16(af[ks], bfr[nt][ks], acc[mt][nt], 0, 0, 0);
    }

    float s[4], q[4];
    #pragma unroll
    for (int nt = 0; nt < 4; ++nt) { s[nt] = 0.f; q[nt] = 0.f; }
    #pragma unroll
    for (int nt = 0; nt < 4; ++nt) {
        const int n = nb + nt * 16 + (lane & 15);
        #pragma unroll
        for (int mt = 0; mt < 4; ++mt)
            #pragma unroll
            for (int r = 0; r < 4; ++r) {
                const int i = i0 + mt * 16 + (lane >> 4) * 4 + r;
                if (i < NN) {
                    const float v = acc[mt][nt][r];
                    s[nt] += v; q[nt] = fmaf(v, v, q[nt]);
                    z1H[(size_t)i * D2 + n] = f2h(v);
                }
            }
    }
    #pragma unroll
    for (int nt = 0; nt < 4; ++nt) {
        s[nt] += __shfl_xor(s[nt], 16, 64); s[nt] += __shfl_xor(s[nt], 32, 64);
        q[nt] += __shfl_xor(q[nt], 16, 64); q[nt] += __shfl_xor(q[nt], 32, 64);
    }
    if (lane < 16) {
        #pragma unroll
        for (int nt = 0; nt < 4; ++nt) {
            const int n = nb + nt * 16 + lane;
            atomAddF(&stats[n], s[nt]);
            atomAddF(&stats[D2 + n], q[nt]);
        }
    }
}

// ---------------- ymean: ysum[c] = sum_rows relu(a*z1c+cc); aff computed inline ----------------
#define YROWS 391
__global__ __launch_bounds__(256)
void ymean_kernel(const ushort_t* __restrict__ z1H, const float* __restrict__ stats1,
                  const float* __restrict__ g1, const float* __restrict__ bt1,
                  float* __restrict__ ysum)
{
    __shared__ float sAf[2 * D2];
    __shared__ float sR[4][D2];
    const int t = threadIdx.x;
    {
        const float inv = 1.0f / (float)NN;
        const float mu = stats1[t] * inv;
        const float var = fmaf(-mu, mu, stats1[D2 + t] * inv);
        const float a = g1[t] * rsqrtf(var + BN_EPS);
        sAf[t] = a;
        sAf[D2 + t] = fmaf(-a, mu, bt1[t]);
    }
    __syncthreads();
    const int c0 = (t & 63) * 4;
    const int rg = t >> 6;
    const float a0 = sAf[c0], a1 = sAf[c0 + 1], a2 = sAf[c0 + 2], a3 = sAf[c0 + 3];
    const float b0 = sAf[D2 + c0], b1 = sAf[D2 + c0 + 1], b2 = sAf[D2 + c0 + 2], b3 = sAf[D2 + c0 + 3];
    float s0 = 0.f, s1 = 0.f, s2 = 0.f, s3 = 0.f;
    const int rend = min(NN, (blockIdx.x + 1) * YROWS);
    for (int r = blockIdx.x * YROWS + rg; r < rend; r += 4) {
        const uint2 v = *(const uint2*)&z1H[(size_t)r * D2 + c0];
        s0 += fmaxf(fmaf(a0, h2f(v.x), b0), 0.f);
        s1 += fmaxf(fmaf(a1, h2f(v.x >> 16), b1), 0.f);
        s2 += fmaxf(fmaf(a2, h2f(v.y), b2), 0.f);
        s3 += fmaxf(fmaf(a3, h2f(v.y >> 16), b3), 0.f);
    }
    sR[rg][c0] = s0; sR[rg][c0 + 1] = s1; sR[rg][c0 + 2] = s2; sR[rg][c0 + 3] = s3;
    __syncthreads();
    if (t < D2) atomAddF(&ysum[t], sR[0][t] + sR[1][t] + sR[2][t] + sR[3][t]);
}

// ---------------- mm2: z2c = (relu(aff1(z1c)) - ymean) @ W2 (fp16 MFMA), fp32 out ----------------
__global__ __launch_bounds__(256, 2)
void mm2_kernel(const ushort_t* __restrict__ z1H, const float* __restrict__ stats1,
                const float* __restrict__ g1, const float* __restrict__ bt1,
                const float* __restrict__ ysum, const ushort_t* __restrict__ W2t,
                float* __restrict__ z2F, float* __restrict__ stats2)
{
    __shared__ __align__(16) ushort_t sA[64 * 256];
    __shared__ __align__(16) float sAff[2 * D2];
    __shared__ __align__(16) float sYm[D2];
    const int t = threadIdx.x;
    {
        const float inv = 1.0f / (float)NN;
        const float mu = stats1[t] * inv;
        const float var = fmaf(-mu, mu, stats1[D2 + t] * inv);
        const float a = g1[t] * rsqrtf(var + BN_EPS);
        sAff[t] = a;
        sAff[D2 + t] = fmaf(-a, mu, bt1[t]);
        sYm[t] = ysum[t] * inv;
    }
    const int i0 = blockIdx.x * 64;
    const int lane = t & 63, w = t >> 6;
    const int nb = w * 32;

    f16x8 bfr[2][8];
    #pragma unroll
    for (int nt = 0; nt < 2; ++nt)
        #pragma unroll
        for (int ks = 0; ks < 8; ++ks) {
            const int n = nb + nt * 16 + (lane & 15);
            const int k = ks * 32 + (lane >> 4) * 8;
            bfr[nt][ks] = *(const f16x8*)&W2t[n * D2 + k];
        }
    __syncthreads();   // sAff/sYm visible

    #pragma unroll
    for (int p = 0; p < 8; ++p) {
        const int linear = p * 256 + t;
        const int row = linear >> 5, ch = linear & 31;
        const int gi = i0 + row;
        uint4 v = make_uint4(0, 0, 0, 0);
        if (gi < NN) v = *(const uint4*)&z1H[(size_t)gi * D2 + ch * 8];
        unsigned uu[4] = {v.x, v.y, v.z, v.w};
        unsigned oo[4] = {0, 0, 0, 0};
        if (gi < NN) {
            #pragma unroll
            for (int j2 = 0; j2 < 4; ++j2) {
                const int c0 = ch * 8 + j2 * 2;
                float lo = h2f(uu[j2]);
                float hi = h2f(uu[j2] >> 16);
                lo = fmaxf(fmaf(sAff[c0], lo, sAff[D2 + c0]), 0.f) - sYm[c0];
                hi = fmaxf(fmaf(sAff[c0 + 1], hi, sAff[D2 + c0 + 1]), 0.f) - sYm[c0 + 1];
                oo[j2] = pk2h(lo, hi);
            }
        }
        unsigned boff = (unsigned)(row * 512 + ch * 16);
        boff ^= (unsigned)((row & 7) << 4);
        *(uint4*)((char*)sA + boff) = make_uint4(oo[0], oo[1], oo[2], oo[3]);
    }
    __syncthreads();

    f32x4 acc[4][2];
    #pragma unroll
    for (int a = 0; a < 4; ++a)
        #pragma unroll
        for (int b = 0; b < 2; ++b) acc[a][b] = (f32x4){0.f, 0.f, 0.f, 0.f};

    #pragma unroll
    for (int mt = 0; mt < 4; ++mt) {
        f16x8 af[8];
        #pragma unroll
        for (int ks = 0; ks < 8; ++ks) {
            const int row = mt * 16 + (lane & 15);
            unsigned boff = (unsigned)(row * 512 + ks * 64 + (lane >> 4) * 16);
            boff ^= (unsigned)((row & 7) << 4);
            af[ks] = *(const f16x8*)((const char*)sA + boff);
        }
        #pragma unroll
        for (int nt = 0; nt < 2; ++nt)
            #pragma unroll
            for (int ks = 0; ks < 8; ++ks)
                acc[mt][nt] = __builtin_amdgcn_mfma_f32_16x16x32_f16(af[ks], bfr[nt][ks], acc[mt][nt], 0, 0, 0);
    }

    float s[2], q[2];
    #pragma unroll
    for (int nt = 0; nt < 2; ++nt) { s[nt] = 0.f; q[nt] = 0.f; }
    #pragma unroll
    for (int nt = 0; nt < 2; ++nt) {
        const int n = nb + nt * 16 + (lane & 15);
        #pragma unroll
        for (int mt = 0; mt < 4; ++mt)
            #pragma unroll
            for (int r = 0; r < 4; ++r) {
                const int i = i0 + mt * 16 + (lane >> 4) * 4 + r;
                if (i < NN) {
                    const float v = acc[mt][nt][r];
                    s[nt] += v; q[nt] = fmaf(v, v, q[nt]);
                    z2F[(size_t)i * D + n] = v;
                }
            }
    }
    #pragma unroll
    for (int nt = 0; nt < 2; ++nt) {
        s[nt] += __shfl_xor(s[nt], 16, 64); s[nt] += __shfl_xor(s[nt], 32, 64);
        q[nt] += __shfl_xor(q[nt], 16, 64); q[nt] += __shfl_xor(q[nt], 32, 64);
    }
    if (lane < 16) {
        #pragma unroll
        for (int nt = 0; nt < 2; ++nt) {
            const int n = nb + nt * 16 + lane;
            atomAddF(&stats2[n], s[nt]);
            atomAddF(&stats2[D + n], q[nt]);
        }
    }
}

// ---------------- act: HALF=1: hAct(fp16) = relu(aff2(z2)); HALF=0: out(fp32) = aff2(z2) ----------------
template<int HALF>
__global__ __launch_bounds__(256)
void act_kernel(const float* __restrict__ z2F, const float* __restrict__ stats2,
                const float* __restrict__ g, const float* __restrict__ bt,
                void* __restrict__ dstv)
{
    __shared__ float sA[D], sC[D];
    const int t = threadIdx.x;
    if (t < D) {
        const float inv = 1.0f / (float)NN;
        const float mu = stats2[t] * inv;
        const float var = fmaf(-mu, mu, stats2[D + t] * inv);
        const float a = g[t] * rsqrtf(var + BN_EPS);
        sA[t] = a;
        sC[t] = fmaf(-a, mu, bt[t]);
    }
    __syncthreads();
    const int idx = blockIdx.x * 256 + t;  // float4 index
    if (idx < NN * D / 4) {
        const int d0 = (idx * 4) & (D - 1);
        const float4 v = *(const float4*)&z2F[(size_t)idx * 4];
        float4 o;
        o.x = fmaf(sA[d0 + 0], v.x, sC[d0 + 0]);
        o.y = fmaf(sA[d0 + 1], v.y, sC[d0 + 1]);
        o.z = fmaf(sA[d0 + 2], v.z, sC[d0 + 2]);
        o.w = fmaf(sA[d0 + 3], v.w, sC[d0 + 3]);
        if (HALF) {
            o.x = fmaxf(o.x, 0.f); o.y = fmaxf(o.y, 0.f);
            o.z = fmaxf(o.z, 0.f); o.w = fmaxf(o.w, 0.f);
            uint2 pkd;
            pkd.x = pk2h(o.x, o.y);
            pkd.y = pk2h(o.z, o.w);
            *((uint2*)dstv + idx) = pkd;
        } else {
            *((float4*)dstv + idx) = o;
        }
    }
}

extern "C" void kernel_launch(void* const* d_in, const int* in_sizes, int n_in,
                              void* d_out, int out_size, void* d_ws, size_t ws_size,
                              hipStream_t stream)
{
    (void)in_sizes; (void)n_in; (void)out_size; (void)ws_size;
    const int*   ei       = (const int*)d_in[1];
    const float* ea       = (const float*)d_in[2];
    const float* node_emb = (const float*)d_in[3];
    const float* We       = (const float*)d_in[4];
    const float* be       = (const float*)d_in[5];
    const float* eps      = (const float*)d_in[6];
    const float* W1       = (const float*)d_in[7];
    const float* g1       = (const float*)d_in[9];
    const float* bt1      = (const float*)d_in[10];
    const float* W2       = (const float*)d_in[11];
    const float* gbn      = (const float*)d_in[13];
    const float* bbn      = (const float*)d_in[14];
    float* out = (float*)d_out;

    char* base = (char*)d_ws;
    size_t off = 0;
    auto alloc = [&](size_t bytes) -> void* {
        void* p = base + off;
        off = (off + bytes + 255) & ~(size_t)255;
        return p;
    };
    float*    tmpF   = (float*)alloc((size_t)NN * D * 4);      // xin (gather->mm1), z2 (mm2->act)
    ushort_t* z1H    = (ushort_t*)alloc((size_t)NN * D2 * 2);
    ushort_t* hAct   = (ushort_t*)alloc((size_t)NN * D * 2);   // fp16 post-BN+relu h
    ushort_t* W1t    = (ushort_t*)alloc((size_t)NL * D * D2 * 2);
    ushort_t* W2t    = (ushort_t*)alloc((size_t)NL * D * D2 * 2);
    float*    red    = (float*)alloc(1152 * sizeof(float));
    float*    stats1 = red;            // 512
    float*    stats2 = red + 512;      // 256
    float*    xsum   = red + 768;      // 128
    float*    ysum   = red + 896;      // 256
    int*      counts = (int*)alloc((NN + 1) * sizeof(int));
    int*      offs   = (int*)alloc((NN + 1) * sizeof(int));
    int*      offmut = (int*)alloc(NN * sizeof(int));
    int*      sSrc   = (int*)alloc((size_t)NE * sizeof(int));
    ushort_t* eaH    = (ushort_t*)alloc((size_t)NE * 8 * 2);

    // ---- CSR build + weight conversion ----
    hipMemsetAsync(counts, 0, (NN + 1) * sizeof(int), stream);
    hist_kernel<<<(NE + 255) / 256, 256, 0, stream>>>(ei, counts);
    scan_kernel<<<1, 1024, 0, stream>>>(counts, offs);
    hipMemcpyAsync(offmut, offs, NN * sizeof(int), hipMemcpyDeviceToDevice, stream);
    scatter_kernel<<<(NE + 255) / 256, 256, 0, stream>>>(ei, ea, offmut, sSrc, eaH);
    wconv_kernel<<<(NL * D * D2 + 255) / 256, 256, 0, stream>>>(W1, W2, W1t, W2t);

    for (int l = 0; l < NL; ++l) {
        hipMemsetAsync(red, 0, 1152 * sizeof(float), stream);
        if (l == 0) {
            gather_kernel<1><<<6250, 256, 0, stream>>>(offs, sSrc, eaH,
                                                       We + l * EF * D, be + l * D,
                                                       hAct, node_emb, eps + l, tmpF, xsum);
        } else {
            gather_kernel<0><<<6250, 256, 0, stream>>>(offs, sSrc, eaH,
                                                       We + l * EF * D, be + l * D,
                                                       hAct, node_emb, eps + l, tmpF, xsum);
        }
        mm1_kernel<<<(NN + 63) / 64, 256, 0, stream>>>(tmpF, xsum, W1t + (size_t)l * D * D2,
                                                       z1H, stats1);
        ymean_kernel<<<256, 256, 0, stream>>>(z1H, stats1, g1 + l * D2, bt1 + l * D2, ysum);
        mm2_kernel<<<(NN + 63) / 64, 256, 0, stream>>>(z1H, stats1, g1 + l * D2, bt1 + l * D2,
                                                       ysum, W2t + (size_t)l * D * D2,
                                                       tmpF, stats2);
        if (l < NL - 1) {
            act_kernel<1><<<(NN * D / 4 + 255) / 256, 256, 0, stream>>>(
                tmpF, stats2, gbn + l * D, bbn + l * D, hAct);
        } else {
            act_kernel<0><<<(NN * D / 4 + 255) / 256, 256, 0, stream>>>(
                tmpF, stats2, gbn + l * D, bbn + l * D, out);
        }
    }
}